// Round 2
// baseline (342.484 us; speedup 1.0000x reference)
//
#include <hip/hip_runtime.h>
#include <stdint.h>

#define N_NODES 100000
#define DIM 64
#define SCAN_CHUNK 1024
#define NCHUNK ((N_NODES + SCAN_CHUNK - 1) / SCAN_CHUNK)   // 98

// ---------------- fallback: plain atomic scatter (round-0 kernel) ----------------
__global__ void spmm_atomic_kernel(const int* __restrict__ row,
                                   const int* __restrict__ col,
                                   const float* __restrict__ A,
                                   const float* __restrict__ X,
                                   float* __restrict__ out,
                                   int E) {
    const long long tid = (long long)blockIdx.x * blockDim.x + threadIdx.x;
    const int e  = (int)(tid >> 4);
    const int f4 = (int)(tid & 15);
    if (e >= E) return;
    const int   r = row[e];
    const int   c = col[e];
    const float a = A[e];
    const float4 x = *reinterpret_cast<const float4*>(X + (size_t)c * DIM + (size_t)f4 * 4);
    float* o = out + (size_t)r * DIM + (size_t)f4 * 4;
    atomicAdd(o + 0, a * x.x);
    atomicAdd(o + 1, a * x.y);
    atomicAdd(o + 2, a * x.z);
    atomicAdd(o + 3, a * x.w);
}

// ---------------- CSR-build pipeline ----------------

// 1) histogram of destination rows
__global__ void hist_kernel(const int* __restrict__ row, int* __restrict__ cnt, int E) {
    int e = blockIdx.x * blockDim.x + threadIdx.x;
    if (e < E) atomicAdd(&cnt[row[e]], 1);
}

// 2a) per-chunk sums (chunk = SCAN_CHUNK counts)
__global__ void chunk_sum_kernel(const int* __restrict__ cnt, int* __restrict__ blk) {
    __shared__ int lds[256];
    const int chunk = blockIdx.x;
    const int base  = chunk * SCAN_CHUNK;
    const int t     = threadIdx.x;
    int s = 0;
    for (int i = t; i < SCAN_CHUNK; i += 256) {
        int gi = base + i;
        s += (gi < N_NODES) ? cnt[gi] : 0;
    }
    lds[t] = s;
    __syncthreads();
    for (int off = 128; off > 0; off >>= 1) {
        if (t < off) lds[t] += lds[t + off];
        __syncthreads();
    }
    if (t == 0) blk[chunk] = lds[0];
}

// 2b) exclusive scan of the (<=128) chunk sums, single block of 128 threads
__global__ void scan_chunks_kernel(int* __restrict__ blk, int nchunk) {
    __shared__ int lds[128];
    const int t = threadIdx.x;
    const int v = (t < nchunk) ? blk[t] : 0;
    lds[t] = v;
    __syncthreads();
    for (int off = 1; off < 128; off <<= 1) {
        int add = (t >= off) ? lds[t - off] : 0;
        __syncthreads();
        lds[t] += add;
        __syncthreads();
    }
    if (t < nchunk) blk[t] = lds[t] - v;   // exclusive
}

// 2c) local exclusive scan within each chunk + chunk base -> off[]; also off[N]=E total
__global__ void local_scan_kernel(const int* __restrict__ cnt, const int* __restrict__ blk,
                                  int* __restrict__ off) {
    __shared__ int lds[256];
    const int chunk = blockIdx.x;
    const int base  = chunk * SCAN_CHUNK;
    const int t     = threadIdx.x;
    const int gi0   = base + t * 4;
    const int c0 = (gi0 + 0 < N_NODES) ? cnt[gi0 + 0] : 0;
    const int c1 = (gi0 + 1 < N_NODES) ? cnt[gi0 + 1] : 0;
    const int c2 = (gi0 + 2 < N_NODES) ? cnt[gi0 + 2] : 0;
    const int c3 = (gi0 + 3 < N_NODES) ? cnt[gi0 + 3] : 0;
    const int tsum = c0 + c1 + c2 + c3;
    lds[t] = tsum;
    __syncthreads();
    for (int o = 1; o < 256; o <<= 1) {
        int add = (t >= o) ? lds[t - o] : 0;
        __syncthreads();
        lds[t] += add;
        __syncthreads();
    }
    const int e0 = lds[t] - tsum + blk[chunk];  // exclusive offset of gi0
    const int e1 = e0 + c0;
    const int e2 = e1 + c1;
    const int e3 = e2 + c2;
    if (gi0 + 0 < N_NODES) off[gi0 + 0] = e0;
    if (gi0 + 1 < N_NODES) off[gi0 + 1] = e1;
    if (gi0 + 2 < N_NODES) off[gi0 + 2] = e2;
    if (gi0 + 3 < N_NODES) off[gi0 + 3] = e3;
    // element N-1 owner writes the grand total
    if (gi0 <= N_NODES - 1 && N_NODES - 1 <= gi0 + 3) {
        int excl[4] = {e0, e1, e2, e3};
        int cs[4]   = {c0, c1, c2, c3};
        int j = N_NODES - 1 - gi0;
        off[N_NODES] = excl[j] + cs[j];
    }
}

// 3) bin the edges: colA[pos] = (col, bits(A))
__global__ void scatter_kernel(const int* __restrict__ row, const int* __restrict__ col,
                               const float* __restrict__ A, const int* __restrict__ off,
                               int* __restrict__ cur, int2* __restrict__ colA, int E) {
    int e = blockIdx.x * blockDim.x + threadIdx.x;
    if (e >= E) return;
    int r   = row[e];
    int pos = off[r] + atomicAdd(&cur[r], 1);
    colA[pos] = make_int2(col[e], __float_as_int(A[e]));
}

// 4) wave-per-node register aggregation; lane = feature dim
__global__ void aggregate_kernel(const int* __restrict__ off, const int2* __restrict__ colA,
                                 const float* __restrict__ X, float* __restrict__ out) {
    const int wave = (int)(((long long)blockIdx.x * blockDim.x + threadIdx.x) >> 6);
    const int lane = threadIdx.x & 63;
    if (wave >= N_NODES) return;
    const int s = off[wave];
    const int e = off[wave + 1];
    float acc = 0.f;
    int k = s;
    for (; k + 1 < e; k += 2) {
        const int2 ca0 = colA[k];
        const int2 ca1 = colA[k + 1];
        const float x0 = X[(size_t)ca0.x * DIM + lane];
        const float x1 = X[(size_t)ca1.x * DIM + lane];
        acc += __int_as_float(ca0.y) * x0 + __int_as_float(ca1.y) * x1;
    }
    if (k < e) {
        const int2 ca = colA[k];
        acc += __int_as_float(ca.y) * X[(size_t)ca.x * DIM + lane];
    }
    out[(size_t)wave * DIM + lane] = acc;   // every node written -> no memset of d_out
}

extern "C" void kernel_launch(void* const* d_in, const int* in_sizes, int n_in,
                              void* d_out, int out_size, void* d_ws, size_t ws_size,
                              hipStream_t stream) {
    const int*   edge_index = (const int*)d_in[0];   // [2,E] flat: row then col
    const float* A_vals     = (const float*)d_in[1];
    const float* X          = (const float*)d_in[2];
    float*       out        = (float*)d_out;

    const int E = in_sizes[0] / 2;
    const int* row = edge_index;
    const int* col = edge_index + E;

    // workspace layout
    char* p = (char*)d_ws;
    int* off = (int*)p;  p += sizeof(int) * (size_t)(N_NODES + 1);
    int* cnt = (int*)p;  p += sizeof(int) * (size_t)N_NODES;
    int* blk = (int*)p;  p += sizeof(int) * 128;
    p = (char*)(((uintptr_t)p + 15) & ~(uintptr_t)15);
    int2* colA = (int2*)p; p += sizeof(int2) * (size_t)E;
    const size_t needed = (size_t)(p - (char*)d_ws);

    if (ws_size < needed) {
        // fallback: atomic scatter
        hipMemsetAsync(out, 0, (size_t)out_size * sizeof(float), stream);
        const long long total = (long long)E * 16;
        spmm_atomic_kernel<<<(int)((total + 255) / 256), 256, 0, stream>>>(row, col, A_vals, X, out, E);
        return;
    }

    // 1) histogram
    hipMemsetAsync(cnt, 0, sizeof(int) * (size_t)N_NODES, stream);
    hist_kernel<<<(E + 255) / 256, 256, 0, stream>>>(row, cnt, E);

    // 2) exclusive scan -> off
    chunk_sum_kernel<<<NCHUNK, 256, 0, stream>>>(cnt, blk);
    scan_chunks_kernel<<<1, 128, 0, stream>>>(blk, NCHUNK);
    local_scan_kernel<<<NCHUNK, 256, 0, stream>>>(cnt, blk, off);

    // 3) bin edges
    hipMemsetAsync(cnt, 0, sizeof(int) * (size_t)N_NODES, stream);
    scatter_kernel<<<(E + 255) / 256, 256, 0, stream>>>(row, col, A_vals, off, cnt, colA, E);

    // 4) aggregate, wave per node
    const long long aggThreads = (long long)N_NODES * 64;
    aggregate_kernel<<<(int)((aggThreads + 255) / 256), 256, 0, stream>>>(off, colA, X, out);
}